// Round 1
// baseline (1255.373 us; speedup 1.0000x reference)
//
#include <hip/hip_runtime.h>

// ---- problem constants ----
#define SIZE   48
#define DESIZE 44
#define PAD    3
#define BATCH  4
#define FLAT   (DESIZE*SIZE*SIZE)      // 101376
#define CVOL   216                     // 6*6*6
#define PD     (DESIZE+6)              // 50
#define PH     (SIZE+6)                // 54
#define PW     (SIZE+6)                // 54
#define PSLICE (PH*PW)                 // 2916
#define PVOL   (PD*PSLICE)             // 145800

// stencil tile: 1 (i) x 4 (j) x 16 (k) voxels per block, 64 voxels
#define TJ 4
#define TK 16
#define NA 6
#define NB (TJ+5)                      // 9
#define NC (TK+5)                      // 21
#define NEU_T (NA*NB*NC)               // 1134
#define SYN_PITCH 217                  // 216+1: lane stride 217 -> bank stride 25, conflict-free

// MLP1 split-K
#define KSLICE  192
#define NSLICES (FLAT/KSLICE)          // 528

__global__ __launch_bounds__(256) void k_init(const float* __restrict__ vin,
                                              const float* __restrict__ frame,
                                              float* __restrict__ A,
                                              float* __restrict__ B) {
    int p = blockIdx.x * 256 + threadIdx.x;
    if (p >= BATCH * PVOL) return;
    int b = p / PVOL, r = p % PVOL;
    int iz = r / PSLICE, r2 = r % PSLICE;
    int iy = r2 / PW, ix = r2 % PW;
    float val = 0.f;
    if (iz >= PAD && iz < PAD + DESIZE && iy >= PAD && iy < PAD + SIZE &&
        ix >= PAD && ix < PAD + SIZE) {
        int v = ((iz - PAD) * SIZE + (iy - PAD)) * SIZE + (ix - PAD);
        val = vin[b * FLAT + v] + frame[v];
    }
    A[p] = val;   // neu0, zero-padded halo
    B[p] = 0.f;   // pads must be zero; interior overwritten by step 1
}

template <int W>
__device__ __forceinline__ float do_chunk(const float* __restrict__ sl,
                                          const float* __restrict__ neu_t,
                                          int lanebase) {
    float acc = 0.f;
#pragma unroll
    for (int s = 0; s < 54; ++s) {
        const int c  = W * 54 + s;          // compile-time after unroll
        const int fd = c / 36;
        const int fh = (c % 36) / 6;
        const int fw = c % 6;
        acc += sl[c] * neu_t[lanebase + fd * (NB * NC) + fh * NC + fw];
    }
    return acc;
}

__global__ __launch_bounds__(256) void k_step(const float* __restrict__ nin,
                                              const float* __restrict__ syn,
                                              float* __restrict__ nout) {
    __shared__ float syn_t[64 * SYN_PITCH];   // 55552 B
    __shared__ float neu_t[NEU_T];            //  4536 B
    __shared__ float part[256];               //  1024 B
    int t = threadIdx.x;
    int bid = blockIdx.x;
    int b  = bid / 1584;
    int r  = bid % 1584;
    int i0 = r / 36;
    int r2 = r % 36;
    int j0 = (r2 / 3) * TJ;
    int k0 = (r2 % 3) * TK;

    // stage neu halo region (padded origin (i0,j0,k0), extent 6x9x21)
    const float* nb_ = nin + (size_t)b * PVOL;
    for (int e = t; e < NEU_T; e += 256) {
        int a   = e / (NB * NC);
        int rem = e % (NB * NC);
        int bb  = rem / NC;
        int cc  = rem % NC;
        neu_t[e] = nb_[(i0 + a) * PSLICE + (j0 + bb) * PW + (k0 + cc)];
    }
    // stage synapse rows for the 64 tile voxels (contiguous runs of 16*216 floats)
    for (int e = t; e < 64 * CVOL; e += 256) {
        int v = e / CVOL, c = e % CVOL;
        int dj = v >> 4, dk = v & 15;
        size_t gi = (size_t)((i0 * SIZE + j0 + dj) * SIZE + k0 + dk) * CVOL + c;
        syn_t[v * SYN_PITCH + c] = syn[gi];
    }
    __syncthreads();

    int w = t >> 6, l = t & 63;
    int dj = l >> 4, dk = l & 15;
    int lanebase = dj * NC + dk;
    const float* sl = syn_t + l * SYN_PITCH;
    float acc;
    switch (w) {
        case 0:  acc = do_chunk<0>(sl, neu_t, lanebase); break;
        case 1:  acc = do_chunk<1>(sl, neu_t, lanebase); break;
        case 2:  acc = do_chunk<2>(sl, neu_t, lanebase); break;
        default: acc = do_chunk<3>(sl, neu_t, lanebase); break;
    }
    part[t] = acc;
    __syncthreads();
    if (t < 64) {
        float s = part[t] + part[64 + t] + part[128 + t] + part[192 + t];
        s = fmaxf(s, 0.f) * 0.9f;
        int dj2 = t >> 4, dk2 = t & 15;
        nout[(size_t)b * PVOL + (i0 + PAD) * PSLICE + (j0 + dj2 + PAD) * PW +
             (k0 + dk2 + PAD)] = s;
    }
}

__global__ __launch_bounds__(256) void k_compact(const float* __restrict__ nf,
                                                 float* __restrict__ xc) {
    int idx = blockIdx.x * 256 + threadIdx.x;
    if (idx >= BATCH * FLAT) return;
    int b = idx / FLAT, v = idx % FLAT;
    int i = v / (SIZE * SIZE), j = (v / SIZE) % SIZE, k = v % SIZE;
    xc[idx] = nf[(size_t)b * PVOL + (i + PAD) * PSLICE + (j + PAD) * PW + (k + PAD)];
}

// x (4 x FLAT) @ W1 (FLAT x 1024), split-K. block: 256 thr, 4 cols/thread (float4).
__global__ __launch_bounds__(256) void k_mlp1(const float* __restrict__ xc,
                                              const float* __restrict__ W1,
                                              float* __restrict__ partial) {
    __shared__ float xs[KSLICE * 4];   // [kk][b]
    int t = threadIdx.x;
    int s = blockIdx.x;
    int k0 = s * KSLICE;
    for (int e = t; e < KSLICE * 4; e += 256) {
        int kk = e >> 2, b = e & 3;
        xs[e] = xc[(size_t)b * FLAT + k0 + kk];
    }
    __syncthreads();
    float acc[4][4] = {};
    const float* wp = W1 + (size_t)k0 * 1024 + t * 4;
#pragma unroll 4
    for (int kk = 0; kk < KSLICE; ++kk) {
        float4 w  = *(const float4*)(wp + (size_t)kk * 1024);
        float4 xv = *(const float4*)(xs + kk * 4);
        acc[0][0] += xv.x * w.x; acc[0][1] += xv.x * w.y; acc[0][2] += xv.x * w.z; acc[0][3] += xv.x * w.w;
        acc[1][0] += xv.y * w.x; acc[1][1] += xv.y * w.y; acc[1][2] += xv.y * w.z; acc[1][3] += xv.y * w.w;
        acc[2][0] += xv.z * w.x; acc[2][1] += xv.z * w.y; acc[2][2] += xv.z * w.z; acc[2][3] += xv.z * w.w;
        acc[3][0] += xv.w * w.x; acc[3][1] += xv.w * w.y; acc[3][2] += xv.w * w.z; acc[3][3] += xv.w * w.w;
    }
#pragma unroll
    for (int b = 0; b < 4; ++b) {
        float4 o = make_float4(acc[b][0], acc[b][1], acc[b][2], acc[b][3]);
        *(float4*)(partial + (size_t)s * 4096 + b * 1024 + t * 4) = o;
    }
}

// reduce NSLICES partials -> h1 = relu(sum + b1). 256 blocks x 256 thr; 16 outputs/block.
__global__ __launch_bounds__(256) void k_reduce1(const float* __restrict__ partial,
                                                 const float* __restrict__ b1,
                                                 float* __restrict__ h1) {
    __shared__ float red[16][17];
    int t = threadIdx.x;
    int e0 = blockIdx.x * 16;
    int eo = t & 15, sl = t >> 4;     // 16 outputs x 16 slice-lanes
    float acc = 0.f;
    for (int it = 0; it < NSLICES / 16; ++it) {
        int s = sl + 16 * it;
        acc += partial[(size_t)s * 4096 + e0 + eo];
    }
    red[sl][eo] = acc;
    __syncthreads();
    if (t < 16) {
        float a = 0.f;
#pragma unroll
        for (int rr = 0; rr < 16; ++rr) a += red[rr][t];
        int e = e0 + t;
        h1[e] = fmaxf(a + b1[e & 1023], 0.f);
    }
}

// h1 (4x1024) @ W2 (1024x128), split-K 8 x 2 col-chunks, 64 thr.
__global__ __launch_bounds__(64) void k_mlp2(const float* __restrict__ h1,
                                             const float* __restrict__ W2,
                                             float* __restrict__ partial2) {
    __shared__ float xs[128 * 4];
    int t = threadIdx.x;
    int bid = blockIdx.x;
    int s = bid >> 1, ch = bid & 1;
    int k0 = s * 128;
    for (int e = t; e < 512; e += 64) {
        int kk = e >> 2, b = e & 3;
        xs[e] = h1[b * 1024 + k0 + kk];
    }
    __syncthreads();
    float acc[4] = {0.f, 0.f, 0.f, 0.f};
    int n2 = ch * 64 + t;
    for (int kk = 0; kk < 128; ++kk) {
        float w = W2[(k0 + kk) * 128 + n2];
        float4 xv = *(const float4*)(xs + kk * 4);
        acc[0] += xv.x * w; acc[1] += xv.y * w; acc[2] += xv.z * w; acc[3] += xv.w * w;
    }
#pragma unroll
    for (int b = 0; b < 4; ++b) partial2[s * 512 + b * 128 + n2] = acc[b];
}

__global__ __launch_bounds__(128) void k_mlp3(const float* __restrict__ partial2,
                                              const float* __restrict__ b2,
                                              const float* __restrict__ W3,
                                              const float* __restrict__ b3,
                                              float* __restrict__ out) {
    __shared__ float h2[512];   // [b][n2]
    int t = threadIdx.x;
    for (int e = t; e < 512; e += 128) {
        int n2 = e & 127;
        float a = b2[n2];
        for (int s = 0; s < 8; ++s) a += partial2[s * 512 + e];
        h2[e] = fmaxf(a, 0.f);
    }
    __syncthreads();
    if (t < 40) {
        int b = t / 10, o = t % 10;
        float a = b3[o];
        for (int k = 0; k < 128; ++k) a += h2[b * 128 + k] * W3[k * 10 + o];
        out[b * 10 + o] = a;
    }
}

extern "C" void kernel_launch(void* const* d_in, const int* in_sizes, int n_in,
                              void* d_out, int out_size, void* d_ws, size_t ws_size,
                              hipStream_t stream) {
    const float* vin   = (const float*)d_in[0];
    const float* frame = (const float*)d_in[1];
    const float* syn   = (const float*)d_in[2];
    const float* W1    = (const float*)d_in[3];
    const float* b1    = (const float*)d_in[4];
    const float* W2    = (const float*)d_in[5];
    const float* b2    = (const float*)d_in[6];
    const float* W3    = (const float*)d_in[7];
    const float* b3    = (const float*)d_in[8];
    float* out = (float*)d_out;

    float* ws = (float*)d_ws;
    float* A   = ws;                         // 583200
    float* B   = A + (size_t)BATCH * PVOL;   // 583200
    float* XC  = B + (size_t)BATCH * PVOL;   // 405504
    float* P1  = XC + (size_t)BATCH * FLAT;  // 528*4096
    float* H1  = P1 + (size_t)NSLICES * 4096;// 4096
    float* P2  = H1 + 4096;                  // 4096

    k_init<<<(BATCH * PVOL + 255) / 256, 256, 0, stream>>>(vin, frame, A, B);

    k_step<<<BATCH * 1584, 256, 0, stream>>>(A, syn, B);
    k_step<<<BATCH * 1584, 256, 0, stream>>>(B, syn, A);
    k_step<<<BATCH * 1584, 256, 0, stream>>>(A, syn, B);
    k_step<<<BATCH * 1584, 256, 0, stream>>>(B, syn, A);
    k_step<<<BATCH * 1584, 256, 0, stream>>>(A, syn, B);

    k_compact<<<(BATCH * FLAT) / 256, 256, 0, stream>>>(B, XC);

    k_mlp1<<<NSLICES, 256, 0, stream>>>(XC, W1, P1);
    k_reduce1<<<256, 256, 0, stream>>>(P1, b1, H1);
    k_mlp2<<<16, 64, 0, stream>>>(H1, W2, P2);
    k_mlp3<<<1, 128, 0, stream>>>(P2, b2, W3, b3, out);
}

// Round 2
// 898.496 us; speedup vs baseline: 1.3972x; 1.3972x over previous
//
#include <hip/hip_runtime.h>

// ---- problem constants ----
#define SIZE   48
#define DESIZE 44
#define PAD    3
#define BATCH  4
#define FLAT   (DESIZE*SIZE*SIZE)      // 101376
#define CVOL   216                     // 6*6*6
#define PD     (DESIZE+6)              // 50
#define PH     (SIZE+6)                // 54
#define PW     (SIZE+6)                // 54
#define PSLICE (PH*PW)                 // 2916
#define PVOL   (PD*PSLICE)             // 145800

// stencil tile: 1 (i) x 4 (j) x 16 (k) voxels per block, 64 voxels, ALL 4 batches
#define TJ 4
#define TK 16
#define NA 6
#define NB (TJ+5)                      // 9
#define NC (TK+5)                      // 21
#define NEU_T (NA*NB*NC)               // 1134
#define SYN_PITCH 217                  // 216+1: lane stride 217 -> bank stride 25, conflict-free reads

// MLP1 split-K
#define KSLICE  192
#define NSLICES (FLAT/KSLICE)          // 528

__global__ __launch_bounds__(256) void k_init(const float* __restrict__ vin,
                                              const float* __restrict__ frame,
                                              float* __restrict__ A,
                                              float* __restrict__ B) {
    int p = blockIdx.x * 256 + threadIdx.x;
    if (p >= BATCH * PVOL) return;
    int b = p / PVOL, r = p % PVOL;
    int iz = r / PSLICE, r2 = r % PSLICE;
    int iy = r2 / PW, ix = r2 % PW;
    float val = 0.f;
    if (iz >= PAD && iz < PAD + DESIZE && iy >= PAD && iy < PAD + SIZE &&
        ix >= PAD && ix < PAD + SIZE) {
        int v = ((iz - PAD) * SIZE + (iy - PAD)) * SIZE + (ix - PAD);
        val = vin[b * FLAT + v] + frame[v];
    }
    A[p] = val;   // neu0, zero-padded halo
    B[p] = 0.f;   // pads must be zero; interior overwritten each step
}

template <int W>
__device__ __forceinline__ void do_chunk4(const float* __restrict__ sl,
                                          const float* __restrict__ neu_t,
                                          int lanebase, float acc[4]) {
#pragma unroll
    for (int s = 0; s < 54; ++s) {
        const int c  = W * 54 + s;          // compile-time after unroll
        const int fd = c / 36;
        const int fh = (c % 36) / 6;
        const int fw = c % 6;
        const int off = lanebase + fd * (NB * NC) + fh * NC + fw;
        float w = sl[c];                    // one syn read feeds 4 batches
        acc[0] += w * neu_t[0 * NEU_T + off];
        acc[1] += w * neu_t[1 * NEU_T + off];
        acc[2] += w * neu_t[2 * NEU_T + off];
        acc[3] += w * neu_t[3 * NEU_T + off];
    }
}

// One block = one 64-voxel tile x ALL 4 batches. grid = 44*36 = 1584.
template <bool LAST>
__global__ __launch_bounds__(256) void k_step(const float* __restrict__ nin,
                                              const float* __restrict__ syn,
                                              float* __restrict__ nout) {
    __shared__ float syn_t[64 * SYN_PITCH];   // 55552 B
    __shared__ float neu_t[4 * NEU_T];        // 18144 B
    __shared__ float part[4 * 256];           //  4096 B
    int t = threadIdx.x;
    int r  = blockIdx.x;                      // 0..1583
    int i0 = r / 36;
    int r2 = r % 36;
    int j0 = (r2 / 3) * TJ;
    int k0 = (r2 % 3) * TK;

    // stage neu halo (6x9x21) for all 4 batches
    for (int bb = 0; bb < 4; ++bb) {
        const float* nb_ = nin + (size_t)bb * PVOL;
        for (int e = t; e < NEU_T; e += 256) {
            int a   = e / (NB * NC);
            int rem = e % (NB * NC);
            int jj  = rem / NC;
            int cc  = rem % NC;
            neu_t[bb * NEU_T + e] = nb_[(i0 + a) * PSLICE + (j0 + jj) * PW + (k0 + cc)];
        }
    }
    // stage synapse rows for the 64 tile voxels, float4 global loads
    for (int e = t; e < 64 * (CVOL / 4); e += 256) {   // 3456 float4
        int v = e / 54, c4 = e % 54;
        int dj = v >> 4, dk = v & 15;
        const float4* s4 = (const float4*)(syn +
            (size_t)((i0 * SIZE + j0 + dj) * SIZE + k0 + dk) * CVOL);
        float4 val = s4[c4];
        float* dst = syn_t + v * SYN_PITCH + c4 * 4;
        dst[0] = val.x; dst[1] = val.y; dst[2] = val.z; dst[3] = val.w;
    }
    __syncthreads();

    int w = t >> 6, l = t & 63;
    int dj = l >> 4, dk = l & 15;
    int lanebase = dj * NC + dk;
    const float* sl = syn_t + l * SYN_PITCH;
    float acc[4] = {0.f, 0.f, 0.f, 0.f};
    switch (w) {
        case 0:  do_chunk4<0>(sl, neu_t, lanebase, acc); break;
        case 1:  do_chunk4<1>(sl, neu_t, lanebase, acc); break;
        case 2:  do_chunk4<2>(sl, neu_t, lanebase, acc); break;
        default: do_chunk4<3>(sl, neu_t, lanebase, acc); break;
    }
#pragma unroll
    for (int bb = 0; bb < 4; ++bb) part[bb * 256 + t] = acc[bb];
    __syncthreads();

    // 256 finals: one (batch, voxel) each
    {
        int bb = t >> 6, lv = t & 63;
        float s = part[bb * 256 + lv] + part[bb * 256 + 64 + lv] +
                  part[bb * 256 + 128 + lv] + part[bb * 256 + 192 + lv];
        s = fmaxf(s, 0.f) * 0.9f;
        int dj2 = lv >> 4, dk2 = lv & 15;
        if (LAST) {
            // write compact MLP-input layout directly
            nout[(size_t)bb * FLAT + (i0 * SIZE + (j0 + dj2)) * SIZE + (k0 + dk2)] = s;
        } else {
            nout[(size_t)bb * PVOL + (i0 + PAD) * PSLICE + (j0 + dj2 + PAD) * PW +
                 (k0 + dk2 + PAD)] = s;
        }
    }
}

// x (4 x FLAT) @ W1 (FLAT x 1024), split-K. block: 256 thr, 4 cols/thread (float4).
__global__ __launch_bounds__(256) void k_mlp1(const float* __restrict__ xc,
                                              const float* __restrict__ W1,
                                              float* __restrict__ partial) {
    __shared__ float xs[KSLICE * 4];   // [kk][b]
    int t = threadIdx.x;
    int s = blockIdx.x;
    int k0 = s * KSLICE;
    for (int e = t; e < KSLICE * 4; e += 256) {
        int kk = e >> 2, b = e & 3;
        xs[e] = xc[(size_t)b * FLAT + k0 + kk];
    }
    __syncthreads();
    float acc[4][4] = {};
    const float* wp = W1 + (size_t)k0 * 1024 + t * 4;
#pragma unroll 8
    for (int kk = 0; kk < KSLICE; ++kk) {
        float4 w  = *(const float4*)(wp + (size_t)kk * 1024);
        float4 xv = *(const float4*)(xs + kk * 4);
        acc[0][0] += xv.x * w.x; acc[0][1] += xv.x * w.y; acc[0][2] += xv.x * w.z; acc[0][3] += xv.x * w.w;
        acc[1][0] += xv.y * w.x; acc[1][1] += xv.y * w.y; acc[1][2] += xv.y * w.z; acc[1][3] += xv.y * w.w;
        acc[2][0] += xv.z * w.x; acc[2][1] += xv.z * w.y; acc[2][2] += xv.z * w.z; acc[2][3] += xv.z * w.w;
        acc[3][0] += xv.w * w.x; acc[3][1] += xv.w * w.y; acc[3][2] += xv.w * w.z; acc[3][3] += xv.w * w.w;
    }
#pragma unroll
    for (int b = 0; b < 4; ++b) {
        float4 o = make_float4(acc[b][0], acc[b][1], acc[b][2], acc[b][3]);
        *(float4*)(partial + (size_t)s * 4096 + b * 1024 + t * 4) = o;
    }
}

// reduce NSLICES partials -> h1 = relu(sum + b1). 256 blocks x 256 thr; 16 outputs/block.
__global__ __launch_bounds__(256) void k_reduce1(const float* __restrict__ partial,
                                                 const float* __restrict__ b1,
                                                 float* __restrict__ h1) {
    __shared__ float red[16][17];
    int t = threadIdx.x;
    int e0 = blockIdx.x * 16;
    int eo = t & 15, sl = t >> 4;     // 16 outputs x 16 slice-lanes
    float acc = 0.f;
    for (int it = 0; it < NSLICES / 16; ++it) {
        int s = sl + 16 * it;
        acc += partial[(size_t)s * 4096 + e0 + eo];
    }
    red[sl][eo] = acc;
    __syncthreads();
    if (t < 16) {
        float a = 0.f;
#pragma unroll
        for (int rr = 0; rr < 16; ++rr) a += red[rr][t];
        int e = e0 + t;
        h1[e] = fmaxf(a + b1[e & 1023], 0.f);
    }
}

// h1 (4x1024) @ W2 (1024x128), split-K 8 x 2 col-chunks, 64 thr.
__global__ __launch_bounds__(64) void k_mlp2(const float* __restrict__ h1,
                                             const float* __restrict__ W2,
                                             float* __restrict__ partial2) {
    __shared__ float xs[128 * 4];
    int t = threadIdx.x;
    int bid = blockIdx.x;
    int s = bid >> 1, ch = bid & 1;
    int k0 = s * 128;
    for (int e = t; e < 512; e += 64) {
        int kk = e >> 2, b = e & 3;
        xs[e] = h1[b * 1024 + k0 + kk];
    }
    __syncthreads();
    float acc[4] = {0.f, 0.f, 0.f, 0.f};
    int n2 = ch * 64 + t;
    for (int kk = 0; kk < 128; ++kk) {
        float w = W2[(k0 + kk) * 128 + n2];
        float4 xv = *(const float4*)(xs + kk * 4);
        acc[0] += xv.x * w; acc[1] += xv.y * w; acc[2] += xv.z * w; acc[3] += xv.w * w;
    }
#pragma unroll
    for (int b = 0; b < 4; ++b) partial2[s * 512 + b * 128 + n2] = acc[b];
}

__global__ __launch_bounds__(128) void k_mlp3(const float* __restrict__ partial2,
                                              const float* __restrict__ b2,
                                              const float* __restrict__ W3,
                                              const float* __restrict__ b3,
                                              float* __restrict__ out) {
    __shared__ float h2[512];   // [b][n2]
    int t = threadIdx.x;
    for (int e = t; e < 512; e += 128) {
        int n2 = e & 127;
        float a = b2[n2];
        for (int s = 0; s < 8; ++s) a += partial2[s * 512 + e];
        h2[e] = fmaxf(a, 0.f);
    }
    __syncthreads();
    if (t < 40) {
        int b = t / 10, o = t % 10;
        float a = b3[o];
        for (int k = 0; k < 128; ++k) a += h2[b * 128 + k] * W3[k * 10 + o];
        out[b * 10 + o] = a;
    }
}

extern "C" void kernel_launch(void* const* d_in, const int* in_sizes, int n_in,
                              void* d_out, int out_size, void* d_ws, size_t ws_size,
                              hipStream_t stream) {
    const float* vin   = (const float*)d_in[0];
    const float* frame = (const float*)d_in[1];
    const float* syn   = (const float*)d_in[2];
    const float* W1    = (const float*)d_in[3];
    const float* b1    = (const float*)d_in[4];
    const float* W2    = (const float*)d_in[5];
    const float* b2    = (const float*)d_in[6];
    const float* W3    = (const float*)d_in[7];
    const float* b3    = (const float*)d_in[8];
    float* out = (float*)d_out;

    float* ws = (float*)d_ws;
    float* A   = ws;                         // 583200
    float* B   = A + (size_t)BATCH * PVOL;   // 583200
    float* XC  = B + (size_t)BATCH * PVOL;   // 405504
    float* P1  = XC + (size_t)BATCH * FLAT;  // 528*4096
    float* H1  = P1 + (size_t)NSLICES * 4096;// 4096
    float* P2  = H1 + 4096;                  // 4096

    k_init<<<(BATCH * PVOL + 255) / 256, 256, 0, stream>>>(vin, frame, A, B);

    k_step<false><<<1584, 256, 0, stream>>>(A, syn, B);
    k_step<false><<<1584, 256, 0, stream>>>(B, syn, A);
    k_step<false><<<1584, 256, 0, stream>>>(A, syn, B);
    k_step<false><<<1584, 256, 0, stream>>>(B, syn, A);
    k_step<true ><<<1584, 256, 0, stream>>>(A, syn, XC);

    k_mlp1<<<NSLICES, 256, 0, stream>>>(XC, W1, P1);
    k_reduce1<<<256, 256, 0, stream>>>(P1, b1, H1);
    k_mlp2<<<16, 64, 0, stream>>>(H1, W2, P2);
    k_mlp3<<<1, 128, 0, stream>>>(P2, b2, W3, b3, out);
}

// Round 3
// 782.903 us; speedup vs baseline: 1.6035x; 1.1476x over previous
//
#include <hip/hip_runtime.h>

// ---- problem constants ----
#define SIZE   48
#define DESIZE 44
#define PAD    3
#define BATCH  4
#define FLAT   (DESIZE*SIZE*SIZE)      // 101376
#define CVOL   216                     // 6*6*6

// stencil tile: 1 (i) x 4 (j) x 16 (k) voxels per block, 64 voxels, ALL 4 batches
#define TJ 4
#define TK 16
#define NA 6
#define NB (TJ+5)                      // 9
#define NC (TK+5)                      // 21
#define NEU_T (NA*NB*NC)               // 1134 halo elements (x4 batches in LDS)
#define SYN_PITCH 217                  // reads syn_t[v*217+c]: bank 25v+c, permutation over lanes -> conflict-free

// MLP1 split-K
#define KSLICE  96
#define NSLICES (FLAT/KSLICE)          // 1056

template <int W>
__device__ __forceinline__ void do_chunk4(const float* __restrict__ sl,
                                          const float* __restrict__ neu_t,
                                          int lanebase, float acc[4]) {
#pragma unroll
    for (int s = 0; s < 54; ++s) {
        const int c  = W * 54 + s;          // compile-time after unroll
        const int fd = c / 36;
        const int fh = (c % 36) / 6;
        const int fw = c % 6;
        const int off = lanebase + fd * (NB * NC) + fh * NC + fw;
        float w = sl[c];                            // 1x ds_read_b32, conflict-free
        const float4 n4 = *(const float4*)(neu_t + off * 4);  // 1x ds_read_b128, all 4 batches
        acc[0] += w * n4.x;
        acc[1] += w * n4.y;
        acc[2] += w * n4.z;
        acc[3] += w * n4.w;
    }
}

// One block = one 64-voxel tile x ALL 4 batches. grid = 44*36 = 1584.
// Compact neu layout [b][i][j][k] (FLAT per batch); halo handled by predicated staging.
template <bool FIRST>
__global__ __launch_bounds__(256) void k_step(const float* __restrict__ nin,
                                              const float* __restrict__ vin,
                                              const float* __restrict__ frame,
                                              const float* __restrict__ syn,
                                              float* __restrict__ nout) {
    __shared__ float syn_t[64 * SYN_PITCH];   // 55552 B, [v][c]
    __shared__ float neu_t[NEU_T * 4];        // 18144 B, [off][batch] -> b128 per off
    __shared__ float part[4 * 256];           //  4096 B
    int t = threadIdx.x;
    int r  = blockIdx.x;                      // 0..1583
    int i0 = r / 36;
    int r2 = r % 36;
    int j0 = (r2 / 3) * TJ;
    int k0 = (r2 % 3) * TK;

    // stage synapse rows for the 64 tile voxels, float4 global loads (coalesced)
    for (int e = t; e < 64 * (CVOL / 4); e += 256) {   // 3456 float4
        int v = e / 54, c4 = e % 54;
        int dj = v >> 4, dk = v & 15;
        const float4* s4 = (const float4*)(syn +
            (size_t)((i0 * SIZE + j0 + dj) * SIZE + k0 + dk) * CVOL);
        float4 val = s4[c4];
        float* dst = syn_t + v * SYN_PITCH + c4 * 4;
        dst[0] = val.x; dst[1] = val.y; dst[2] = val.z; dst[3] = val.w;
    }
    // stage neu halo (6x9x21) for all 4 batches, [off][batch] layout, zero-padded
    for (int e = t; e < NEU_T; e += 256) {
        int a   = e / (NB * NC);
        int rem = e % (NB * NC);
        int jj  = rem / NC;
        int cc  = rem % NC;
        int gi = i0 + a - PAD;
        int gj = j0 + jj - PAD;
        int gk = k0 + cc - PAD;
        float4 vv = make_float4(0.f, 0.f, 0.f, 0.f);
        if ((unsigned)gi < DESIZE && (unsigned)gj < SIZE && (unsigned)gk < SIZE) {
            int idx = (gi * SIZE + gj) * SIZE + gk;
            if (FIRST) {
                float fr = frame[idx];
                vv.x = vin[0 * FLAT + idx] + fr;
                vv.y = vin[1 * FLAT + idx] + fr;
                vv.z = vin[2 * FLAT + idx] + fr;
                vv.w = vin[3 * FLAT + idx] + fr;
            } else {
                vv.x = nin[0 * FLAT + idx];
                vv.y = nin[1 * FLAT + idx];
                vv.z = nin[2 * FLAT + idx];
                vv.w = nin[3 * FLAT + idx];
            }
        }
        *(float4*)(neu_t + e * 4) = vv;   // ds_write_b128, conflict-free
    }
    __syncthreads();

    int w = t >> 6, l = t & 63;
    int dj = l >> 4, dk = l & 15;
    int lanebase = dj * NC + dk;
    const float* sl = syn_t + l * SYN_PITCH;
    float acc[4] = {0.f, 0.f, 0.f, 0.f};
    switch (w) {
        case 0:  do_chunk4<0>(sl, neu_t, lanebase, acc); break;
        case 1:  do_chunk4<1>(sl, neu_t, lanebase, acc); break;
        case 2:  do_chunk4<2>(sl, neu_t, lanebase, acc); break;
        default: do_chunk4<3>(sl, neu_t, lanebase, acc); break;
    }
#pragma unroll
    for (int bb = 0; bb < 4; ++bb) part[bb * 256 + t] = acc[bb];
    __syncthreads();

    // 256 finals: one (batch, voxel) each
    {
        int bb = t >> 6, lv = t & 63;
        float s = part[bb * 256 + lv] + part[bb * 256 + 64 + lv] +
                  part[bb * 256 + 128 + lv] + part[bb * 256 + 192 + lv];
        s = fmaxf(s, 0.f) * 0.9f;
        int dj2 = lv >> 4, dk2 = lv & 15;
        nout[(size_t)bb * FLAT + (i0 * SIZE + (j0 + dj2)) * SIZE + (k0 + dk2)] = s;
    }
}

// x (4 x FLAT) @ W1 (FLAT x 1024), split-K. block: 256 thr, 4 cols/thread (float4).
__global__ __launch_bounds__(256) void k_mlp1(const float* __restrict__ xc,
                                              const float* __restrict__ W1,
                                              float* __restrict__ partial) {
    __shared__ float xs[KSLICE * 4];   // [kk][b]
    int t = threadIdx.x;
    int s = blockIdx.x;
    int k0 = s * KSLICE;
    for (int e = t; e < KSLICE * 4; e += 256) {
        int kk = e >> 2, b = e & 3;
        xs[e] = xc[(size_t)b * FLAT + k0 + kk];
    }
    __syncthreads();
    float acc[4][4] = {};
    const float* wp = W1 + (size_t)k0 * 1024 + t * 4;
#pragma unroll 8
    for (int kk = 0; kk < KSLICE; ++kk) {
        float4 w  = *(const float4*)(wp + (size_t)kk * 1024);
        float4 xv = *(const float4*)(xs + kk * 4);
        acc[0][0] += xv.x * w.x; acc[0][1] += xv.x * w.y; acc[0][2] += xv.x * w.z; acc[0][3] += xv.x * w.w;
        acc[1][0] += xv.y * w.x; acc[1][1] += xv.y * w.y; acc[1][2] += xv.y * w.z; acc[1][3] += xv.y * w.w;
        acc[2][0] += xv.z * w.x; acc[2][1] += xv.z * w.y; acc[2][2] += xv.z * w.z; acc[2][3] += xv.z * w.w;
        acc[3][0] += xv.w * w.x; acc[3][1] += xv.w * w.y; acc[3][2] += xv.w * w.z; acc[3][3] += xv.w * w.w;
    }
#pragma unroll
    for (int b = 0; b < 4; ++b) {
        float4 o = make_float4(acc[b][0], acc[b][1], acc[b][2], acc[b][3]);
        *(float4*)(partial + (size_t)s * 4096 + b * 1024 + t * 4) = o;
    }
}

// reduce NSLICES partials -> h1 = relu(sum + b1). 256 blocks x 256 thr; 16 outputs/block.
__global__ __launch_bounds__(256) void k_reduce1(const float* __restrict__ partial,
                                                 const float* __restrict__ b1,
                                                 float* __restrict__ h1) {
    __shared__ float red[16][17];
    int t = threadIdx.x;
    int e0 = blockIdx.x * 16;
    int eo = t & 15, sl = t >> 4;     // 16 outputs x 16 slice-lanes
    float acc = 0.f;
    for (int it = 0; it < NSLICES / 16; ++it) {
        int s = sl + 16 * it;
        acc += partial[(size_t)s * 4096 + e0 + eo];
    }
    red[sl][eo] = acc;
    __syncthreads();
    if (t < 16) {
        float a = 0.f;
#pragma unroll
        for (int rr = 0; rr < 16; ++rr) a += red[rr][t];
        int e = e0 + t;
        h1[e] = fmaxf(a + b1[e & 1023], 0.f);
    }
}

// h1 (4x1024) @ W2 (1024x128), split-K 8 x 2 col-chunks, 64 thr.
__global__ __launch_bounds__(64) void k_mlp2(const float* __restrict__ h1,
                                             const float* __restrict__ W2,
                                             float* __restrict__ partial2) {
    __shared__ float xs[128 * 4];
    int t = threadIdx.x;
    int bid = blockIdx.x;
    int s = bid >> 1, ch = bid & 1;
    int k0 = s * 128;
    for (int e = t; e < 512; e += 64) {
        int kk = e >> 2, b = e & 3;
        xs[e] = h1[b * 1024 + k0 + kk];
    }
    __syncthreads();
    float acc[4] = {0.f, 0.f, 0.f, 0.f};
    int n2 = ch * 64 + t;
    for (int kk = 0; kk < 128; ++kk) {
        float w = W2[(k0 + kk) * 128 + n2];
        float4 xv = *(const float4*)(xs + kk * 4);
        acc[0] += xv.x * w; acc[1] += xv.y * w; acc[2] += xv.z * w; acc[3] += xv.w * w;
    }
#pragma unroll
    for (int b = 0; b < 4; ++b) partial2[s * 512 + b * 128 + n2] = acc[b];
}

__global__ __launch_bounds__(128) void k_mlp3(const float* __restrict__ partial2,
                                              const float* __restrict__ b2,
                                              const float* __restrict__ W3,
                                              const float* __restrict__ b3,
                                              float* __restrict__ out) {
    __shared__ float h2[512];   // [b][n2]
    int t = threadIdx.x;
    for (int e = t; e < 512; e += 128) {
        int n2 = e & 127;
        float a = b2[n2];
        for (int s = 0; s < 8; ++s) a += partial2[s * 512 + e];
        h2[e] = fmaxf(a, 0.f);
    }
    __syncthreads();
    if (t < 40) {
        int b = t / 10, o = t % 10;
        float a = b3[o];
        for (int k = 0; k < 128; ++k) a += h2[b * 128 + k] * W3[k * 10 + o];
        out[b * 10 + o] = a;
    }
}

extern "C" void kernel_launch(void* const* d_in, const int* in_sizes, int n_in,
                              void* d_out, int out_size, void* d_ws, size_t ws_size,
                              hipStream_t stream) {
    const float* vin   = (const float*)d_in[0];
    const float* frame = (const float*)d_in[1];
    const float* syn   = (const float*)d_in[2];
    const float* W1    = (const float*)d_in[3];
    const float* b1    = (const float*)d_in[4];
    const float* W2    = (const float*)d_in[5];
    const float* b2    = (const float*)d_in[6];
    const float* W3    = (const float*)d_in[7];
    const float* b3    = (const float*)d_in[8];
    float* out = (float*)d_out;

    float* ws = (float*)d_ws;
    float* A   = ws;                          // BATCH*FLAT = 405504
    float* B   = A + (size_t)BATCH * FLAT;    // 405504
    float* P1  = B + (size_t)BATCH * FLAT;    // 1056*4096
    float* H1  = P1 + (size_t)NSLICES * 4096; // 4096
    float* P2  = H1 + 4096;                   // 4096

    k_step<true ><<<1584, 256, 0, stream>>>(nullptr, vin, frame, syn, A);
    k_step<false><<<1584, 256, 0, stream>>>(A, nullptr, nullptr, syn, B);
    k_step<false><<<1584, 256, 0, stream>>>(B, nullptr, nullptr, syn, A);
    k_step<false><<<1584, 256, 0, stream>>>(A, nullptr, nullptr, syn, B);
    k_step<false><<<1584, 256, 0, stream>>>(B, nullptr, nullptr, syn, A);

    k_mlp1<<<NSLICES, 256, 0, stream>>>(A, W1, P1);
    k_reduce1<<<256, 256, 0, stream>>>(P1, b1, H1);
    k_mlp2<<<16, 64, 0, stream>>>(H1, W2, P2);
    k_mlp3<<<1, 128, 0, stream>>>(P2, b2, W3, b3, out);
}